// Round 1
// baseline (578.430 us; speedup 1.0000x reference)
//
#include <hip/hip_runtime.h>

#define D 64
#define EPS 1e-5f

// ---------------- CSR build ----------------

__global__ void hist_k(const int* __restrict__ dst, int* __restrict__ cnt, int e) {
  int i = blockIdx.x * blockDim.x + threadIdx.x;
  if (i < e) atomicAdd(&cnt[dst[i]], 1);
}

__global__ void scan_a_k(const int* __restrict__ cnt, int* __restrict__ rp,
                         int* __restrict__ bsum, int n) {
  __shared__ int sm[256];
  int t = threadIdx.x, i = blockIdx.x * 256 + t;
  int v = (i < n) ? cnt[i] : 0;
  sm[t] = v; __syncthreads();
  for (int off = 1; off < 256; off <<= 1) {
    int x = (t >= off) ? sm[t - off] : 0; __syncthreads();
    sm[t] += x; __syncthreads();
  }
  if (i < n) rp[i] = sm[t] - v;             // exclusive within block
  if (t == 255) bsum[blockIdx.x] = sm[t];   // block total
}

__global__ void scan_b_k(const int* __restrict__ bsum, int* __restrict__ boff, int nb) {
  __shared__ int sm[512];
  int t = threadIdx.x;
  int v = (t < nb) ? bsum[t] : 0;
  sm[t] = v; __syncthreads();
  for (int off = 1; off < 512; off <<= 1) {
    int x = (t >= off) ? sm[t - off] : 0; __syncthreads();
    sm[t] += x; __syncthreads();
  }
  boff[t] = sm[t] - v;                      // exclusive block offsets
}

__global__ void scan_c_k(const int* __restrict__ cnt, int* __restrict__ rp,
                         const int* __restrict__ boff, int* __restrict__ cursor,
                         float* __restrict__ dis, int n, int etot) {
  int i = blockIdx.x * blockDim.x + threadIdx.x;
  if (i < n) {
    int r = rp[i] + boff[i >> 8];
    rp[i] = r;
    cursor[i] = r;
    dis[i] = rsqrtf((float)cnt[i] + 1.0f);  // deg includes self-loop
  }
  if (i == 0) rp[n] = etot;
}

__global__ void fill_k(const int* __restrict__ src, const int* __restrict__ dst,
                       int* __restrict__ cursor, const float* __restrict__ dis,
                       int* __restrict__ col, float* __restrict__ wgt, int e) {
  int i = blockIdx.x * blockDim.x + threadIdx.x;
  if (i < e) {
    int s = src[i], d = dst[i];
    int pos = atomicAdd(&cursor[d], 1);
    col[pos] = s;
    wgt[pos] = dis[s] * dis[d];
  }
}

// ---------------- BN/bias folding: out = maybe_relu(agg*scale + shift) ----------------

__global__ void bnprep_k(const float* __restrict__ b1, const float* __restrict__ b2,
                         const float* __restrict__ b3,
                         const float* __restrict__ g1, const float* __restrict__ be1,
                         const float* __restrict__ rm1, const float* __restrict__ rv1,
                         const float* __restrict__ g2, const float* __restrict__ be2,
                         const float* __restrict__ rm2, const float* __restrict__ rv2,
                         float* __restrict__ scsh) {
  int t = threadIdx.x;
  int j = t & 63, l = t >> 6;
  float sc, sh;
  if (l == 0)      { sc = g1[j] * rsqrtf(rv1[j] + EPS); sh = (b1[j] - rm1[j]) * sc + be1[j]; }
  else if (l == 1) { sc = g2[j] * rsqrtf(rv2[j] + EPS); sh = (b2[j] - rm2[j]) * sc + be2[j]; }
  else             { sc = 1.0f;                          sh = b3[j]; }
  scsh[l * 128 + j] = sc;
  scsh[l * 128 + 64 + j] = sh;
}

// ---------------- GEMM: out[r][j] = sum_k in[r][k] * W[k][j] ----------------
// Wave holds one W column in 64 VGPRs (lane j = column j); row index forced
// wave-uniform via readfirstlane so row loads can scalarize (s_load + v_fmac v,s,v).

__global__ __launch_bounds__(256) void gemm_k(const float* __restrict__ in,
                                              const float* __restrict__ W,
                                              float* __restrict__ out, int nrows) {
  int lane = threadIdx.x & 63;
  float Wc[D];
#pragma unroll
  for (int k = 0; k < D; ++k) Wc[k] = W[k * D + lane];
  int wid = __builtin_amdgcn_readfirstlane((blockIdx.x * blockDim.x + threadIdx.x) >> 6);
  int nw  = (gridDim.x * blockDim.x) >> 6;
  for (int r = wid; r < nrows; r += nw) {
    const float* __restrict__ row = in + (size_t)r * D;
    float a0 = 0.f, a1 = 0.f, a2 = 0.f, a3 = 0.f;
#pragma unroll
    for (int k = 0; k < D; k += 4) {
      a0 = fmaf(row[k],     Wc[k],     a0);
      a1 = fmaf(row[k + 1], Wc[k + 1], a1);
      a2 = fmaf(row[k + 2], Wc[k + 2], a2);
      a3 = fmaf(row[k + 3], Wc[k + 3], a3);
    }
    out[(size_t)r * D + lane] = (a0 + a1) + (a2 + a3);
  }
}

// ---------------- Aggregation: one wave per dst node, lane = feature ----------------

template <bool RELU>
__global__ __launch_bounds__(256) void agg_k(const float* __restrict__ h2,
                                             const int* __restrict__ rp,
                                             const int* __restrict__ col,
                                             const float* __restrict__ wgt,
                                             const float* __restrict__ dis,
                                             const float* __restrict__ scsh,
                                             float* __restrict__ out, int n) {
  int lane = threadIdx.x & 63;
  int node = __builtin_amdgcn_readfirstlane((blockIdx.x * blockDim.x + threadIdx.x) >> 6);
  if (node >= n) return;
  float di  = dis[node];
  float acc = di * di * h2[(size_t)node * D + lane];   // self-loop term
  int p  = rp[node];
  int p1 = rp[node + 1];
  for (; p + 1 < p1; p += 2) {
    int   s0 = col[p],   s1 = col[p + 1];
    float w0 = wgt[p],   w1 = wgt[p + 1];
    float v0 = h2[(size_t)s0 * D + lane];
    float v1 = h2[(size_t)s1 * D + lane];
    acc = fmaf(w0, v0, acc);
    acc = fmaf(w1, v1, acc);
  }
  if (p < p1) acc = fmaf(wgt[p], h2[(size_t)col[p] * D + lane], acc);
  float r = fmaf(acc, scsh[lane], scsh[64 + lane]);
  if (RELU) r = fmaxf(r, 0.0f);
  out[(size_t)node * D + lane] = r;
}

// ---------------- Global mean pool (batch is sorted) ----------------

__global__ __launch_bounds__(256) void pool_k(const float* __restrict__ h,
                                              const int* __restrict__ batch,
                                              float* __restrict__ psum,
                                              float* __restrict__ pcnt, int n) {
  int lane  = threadIdx.x & 63;
  int wid   = __builtin_amdgcn_readfirstlane((blockIdx.x * blockDim.x + threadIdx.x) >> 6);
  int start = wid * 64;
  if (start >= n) return;
  int end = min(start + 64, n);
  int cur = batch[start];
  float sum = 0.f;
  int run = 0;
  for (int i = start; i < end; ++i) {
    int g = batch[i];                       // wave-uniform
    if (g != cur) {
      atomicAdd(&psum[cur * D + lane], sum);
      if (lane == 0) atomicAdd(&pcnt[cur], (float)run);
      sum = 0.f; run = 0; cur = g;
    }
    sum += h[(size_t)i * D + lane];
    run += 1;
  }
  atomicAdd(&psum[cur * D + lane], sum);
  if (lane == 0) atomicAdd(&pcnt[cur], (float)run);
}

__global__ void pooldiv_k(const float* __restrict__ psum, const float* __restrict__ pcnt,
                          float* __restrict__ hg) {
  int t = blockIdx.x * blockDim.x + threadIdx.x;
  if (t < 64 * D) hg[t] = psum[t] / fmaxf(pcnt[t >> 6], 1.0f);
}

// ---------------- launcher ----------------

extern "C" void kernel_launch(void* const* d_in, const int* in_sizes, int n_in,
                              void* d_out, int out_size, void* d_ws, size_t ws_size,
                              hipStream_t stream) {
  const float* x   = (const float*)d_in[0];
  const int*   ei  = (const int*)d_in[1];
  const int*   bat = (const int*)d_in[2];
  const float* W1  = (const float*)d_in[3];
  const float* W2  = (const float*)d_in[4];
  const float* W3  = (const float*)d_in[5];
  const float* b1  = (const float*)d_in[6];
  const float* b2  = (const float*)d_in[7];
  const float* b3  = (const float*)d_in[8];
  const float* g1  = (const float*)d_in[9];
  const float* be1 = (const float*)d_in[10];
  const float* rm1 = (const float*)d_in[11];
  const float* rv1 = (const float*)d_in[12];
  const float* g2  = (const float*)d_in[13];
  const float* be2 = (const float*)d_in[14];
  const float* rm2 = (const float*)d_in[15];
  const float* rv2 = (const float*)d_in[16];

  const int n = in_sizes[0] / D;   // 100000
  const int e = in_sizes[1] / 2;   // 1200000
  const int* src = ei;
  const int* dst = ei + e;

  char* ws = (char*)d_ws;
  size_t off = 0;
  auto alloc = [&](size_t bytes) -> void* {
    void* p = ws + off;
    off = (off + bytes + 255) & ~(size_t)255;
    return p;
  };
  float* bufA   = (float*)alloc((size_t)n * D * 4);
  float* bufB   = (float*)alloc((size_t)n * D * 4);
  int*   cnt    = (int*)alloc((size_t)n * 4);
  int*   rp     = (int*)alloc((size_t)(n + 1) * 4);
  int*   cursor = (int*)alloc((size_t)n * 4);
  float* dis    = (float*)alloc((size_t)n * 4);
  int*   col    = (int*)alloc((size_t)e * 4);
  float* wgt    = (float*)alloc((size_t)e * 4);
  int*   bsum   = (int*)alloc(512 * 4);
  int*   boff   = (int*)alloc(512 * 4);
  float* scsh   = (float*)alloc(6 * 64 * 4);
  float* psum   = (float*)alloc(64 * D * 4);
  float* pcnt   = (float*)alloc(64 * 4);

  float* hout = (float*)d_out;                    // [N, D]
  float* hg   = (float*)d_out + (size_t)n * D;    // [G, D]

  hipMemsetAsync(cnt,  0, (size_t)n * 4, stream);
  hipMemsetAsync(psum, 0, 64 * D * 4, stream);
  hipMemsetAsync(pcnt, 0, 64 * 4, stream);

  const int nb = (n + 255) / 256;
  hist_k<<<(e + 255) / 256, 256, 0, stream>>>(dst, cnt, e);
  scan_a_k<<<nb, 256, 0, stream>>>(cnt, rp, bsum, n);
  scan_b_k<<<1, 512, 0, stream>>>(bsum, boff, nb);
  scan_c_k<<<nb, 256, 0, stream>>>(cnt, rp, boff, cursor, dis, n, e);
  fill_k<<<(e + 255) / 256, 256, 0, stream>>>(src, dst, cursor, dis, col, wgt, e);
  bnprep_k<<<1, 192, 0, stream>>>(b1, b2, b3, g1, be1, rm1, rv1, g2, be2, rm2, rv2, scsh);

  const int gemm_blocks = 2048;              // 8192 waves, ~12 rows/wave
  const int agg_blocks  = (n * 64 + 255) / 256;

  // layer 1
  gemm_k<<<gemm_blocks, 256, 0, stream>>>(x, W1, bufA, n);
  agg_k<true><<<agg_blocks, 256, 0, stream>>>(bufA, rp, col, wgt, dis, scsh + 0 * 128, bufB, n);
  // layer 2
  gemm_k<<<gemm_blocks, 256, 0, stream>>>(bufB, W2, bufA, n);
  agg_k<true><<<agg_blocks, 256, 0, stream>>>(bufA, rp, col, wgt, dis, scsh + 1 * 128, bufB, n);
  // layer 3 (no BN/ReLU; shift = b3)
  gemm_k<<<gemm_blocks, 256, 0, stream>>>(bufB, W3, bufA, n);
  agg_k<false><<<agg_blocks, 256, 0, stream>>>(bufA, rp, col, wgt, dis, scsh + 2 * 128, hout, n);

  // pooling
  const int pool_waves = (n + 63) / 64;
  pool_k<<<(pool_waves * 64 + 255) / 256, 256, 0, stream>>>(hout, bat, psum, pcnt, n);
  pooldiv_k<<<(64 * D + 255) / 256, 256, 0, stream>>>(psum, pcnt, hg);
}

// Round 2
// 505.501 us; speedup vs baseline: 1.1443x; 1.1443x over previous
//
#include <hip/hip_runtime.h>

#define D 64
#define EPS 1e-5f

// ---------------- CSR build ----------------

__global__ void hist_k(const int* __restrict__ dst, int* __restrict__ cnt, int e) {
  int i = blockIdx.x * blockDim.x + threadIdx.x;
  if (i < e) atomicAdd(&cnt[dst[i]], 1);
}

__global__ void scan_a_k(const int* __restrict__ cnt, int* __restrict__ rp,
                         int* __restrict__ bsum, int n) {
  __shared__ int sm[256];
  int t = threadIdx.x, i = blockIdx.x * 256 + t;
  int v = (i < n) ? cnt[i] : 0;
  sm[t] = v; __syncthreads();
  for (int off = 1; off < 256; off <<= 1) {
    int x = (t >= off) ? sm[t - off] : 0; __syncthreads();
    sm[t] += x; __syncthreads();
  }
  if (i < n) rp[i] = sm[t] - v;             // exclusive within block
  if (t == 255) bsum[blockIdx.x] = sm[t];   // block total
}

__global__ void scan_b_k(const int* __restrict__ bsum, int* __restrict__ boff, int nb) {
  __shared__ int sm[512];
  int t = threadIdx.x;
  int v = (t < nb) ? bsum[t] : 0;
  sm[t] = v; __syncthreads();
  for (int off = 1; off < 512; off <<= 1) {
    int x = (t >= off) ? sm[t - off] : 0; __syncthreads();
    sm[t] += x; __syncthreads();
  }
  boff[t] = sm[t] - v;                      // exclusive block offsets
}

__global__ void scan_c_k(const int* __restrict__ cnt, int* __restrict__ rp,
                         const int* __restrict__ boff, int* __restrict__ cursor,
                         float* __restrict__ dis, int n, int etot) {
  int i = blockIdx.x * blockDim.x + threadIdx.x;
  if (i < n) {
    int r = rp[i] + boff[i >> 8];
    rp[i] = r;
    cursor[i] = r;
    dis[i] = rsqrtf((float)cnt[i] + 1.0f);  // deg includes self-loop
  }
  if (i == 0) rp[n] = etot;
}

// col-only fill: weights recomputed on the fly in agg (halves scatter traffic)
__global__ void fill_k(const int* __restrict__ src, const int* __restrict__ dst,
                       int* __restrict__ cursor, int* __restrict__ col, int e) {
  int i = blockIdx.x * blockDim.x + threadIdx.x;
  if (i < e) {
    int s = src[i], d = dst[i];
    int pos = atomicAdd(&cursor[d], 1);
    col[pos] = s;
  }
}

// ---------------- BN/bias folding: out = maybe_relu(agg*scale + shift) ----------------

__global__ void bnprep_k(const float* __restrict__ b1, const float* __restrict__ b2,
                         const float* __restrict__ b3,
                         const float* __restrict__ g1, const float* __restrict__ be1,
                         const float* __restrict__ rm1, const float* __restrict__ rv1,
                         const float* __restrict__ g2, const float* __restrict__ be2,
                         const float* __restrict__ rm2, const float* __restrict__ rv2,
                         float* __restrict__ scsh) {
  int t = threadIdx.x;
  int j = t & 63, l = t >> 6;
  float sc, sh;
  if (l == 0)      { sc = g1[j] * rsqrtf(rv1[j] + EPS); sh = (b1[j] - rm1[j]) * sc + be1[j]; }
  else if (l == 1) { sc = g2[j] * rsqrtf(rv2[j] + EPS); sh = (b2[j] - rm2[j]) * sc + be2[j]; }
  else             { sc = 1.0f;                          sh = b3[j]; }
  scsh[l * 128 + j] = sc;
  scsh[l * 128 + 64 + j] = sh;
}

// ---------------- GEMM: out[r][j] = sum_k in[r][k] * W[k][j] ----------------
// LDS-tiled: 128 rows x 64 cols per block of 256 threads; micro-tile 8x4.
// X tile stored transposed (xt[k][r], ld=132) so A-reads are ds_read_b128.

#define GT_R 128
#define XT_LD 132   // 128 + 4 pad: keeps 16B alignment for b128

__global__ __launch_bounds__(256) void gemm_k(const float* __restrict__ in,
                                              const float* __restrict__ W,
                                              float* __restrict__ out, int nrows) {
  __shared__ float ws[64 * 64];        // W[k][c], 16 KB
  __shared__ float xt[64 * XT_LD];     // X^T [k][r], 33 KB

  const int t    = threadIdx.x;
  const int lane = t & 63;
  const int w    = t >> 6;             // wave 0..3
  const int row0 = blockIdx.x * GT_R;

  // stage W (coalesced float4)
  for (int i = t; i < 1024; i += 256)
    ((float4*)ws)[i] = ((const float4*)W)[i];

  // stage X transposed: instruction = one full row (64 lanes x 4B, coalesced);
  // thread accumulates 4 consecutive rows of its column (lane) -> one b128 write.
#pragma unroll
  for (int j = 0; j < 8; ++j) {
    int Q = w + 4 * j;                 // quad 0..31
    int r = row0 + 4 * Q;
    float4 v;
    v.x = (r + 0 < nrows) ? in[(size_t)(r + 0) * D + lane] : 0.f;
    v.y = (r + 1 < nrows) ? in[(size_t)(r + 1) * D + lane] : 0.f;
    v.z = (r + 2 < nrows) ? in[(size_t)(r + 2) * D + lane] : 0.f;
    v.w = (r + 3 < nrows) ? in[(size_t)(r + 3) * D + lane] : 0.f;
    *(float4*)&xt[lane * XT_LD + 4 * Q] = v;
  }
  __syncthreads();

  const int cq = (t & 15) * 4;         // col start (0..60)
  const int rg = (t >> 4) * 8;         // row start within tile (0..120)
  float acc[8][4] = {};

#pragma unroll 4
  for (int k = 0; k < 64; ++k) {
    float4 b   = *(const float4*)&ws[k * 64 + cq];
    float4 alo = *(const float4*)&xt[k * XT_LD + rg];
    float4 ahi = *(const float4*)&xt[k * XT_LD + rg + 4];
    const float ar[8] = {alo.x, alo.y, alo.z, alo.w, ahi.x, ahi.y, ahi.z, ahi.w};
#pragma unroll
    for (int i = 0; i < 8; ++i) {
      acc[i][0] = fmaf(ar[i], b.x, acc[i][0]);
      acc[i][1] = fmaf(ar[i], b.y, acc[i][1]);
      acc[i][2] = fmaf(ar[i], b.z, acc[i][2]);
      acc[i][3] = fmaf(ar[i], b.w, acc[i][3]);
    }
  }

#pragma unroll
  for (int i = 0; i < 8; ++i) {
    int r = row0 + rg + i;
    if (r < nrows) {
      float4 v = make_float4(acc[i][0], acc[i][1], acc[i][2], acc[i][3]);
      *(float4*)&out[(size_t)r * D + cq] = v;
    }
  }
}

// ---------------- Aggregation: one wave per dst node, lane = feature ----------------
// Edge weight dis[src]*dis[dst] computed on the fly (no wgt array).

template <bool RELU>
__global__ __launch_bounds__(256) void agg_k(const float* __restrict__ h2,
                                             const int* __restrict__ rp,
                                             const int* __restrict__ col,
                                             const float* __restrict__ dis,
                                             const float* __restrict__ scsh,
                                             float* __restrict__ out, int n) {
  int lane = threadIdx.x & 63;
  int node = __builtin_amdgcn_readfirstlane((blockIdx.x * blockDim.x + threadIdx.x) >> 6);
  if (node >= n) return;
  float di  = dis[node];
  float acc = di * di * h2[(size_t)node * D + lane];   // self-loop term
  int p  = rp[node];
  int p1 = rp[node + 1];
  for (; p + 3 < p1; p += 4) {
    int s0 = col[p], s1 = col[p + 1], s2 = col[p + 2], s3 = col[p + 3];
    float w0 = dis[s0] * di, w1 = dis[s1] * di;
    float w2 = dis[s2] * di, w3 = dis[s3] * di;
    float v0 = h2[(size_t)s0 * D + lane];
    float v1 = h2[(size_t)s1 * D + lane];
    float v2 = h2[(size_t)s2 * D + lane];
    float v3 = h2[(size_t)s3 * D + lane];
    acc = fmaf(w0, v0, acc);
    acc = fmaf(w1, v1, acc);
    acc = fmaf(w2, v2, acc);
    acc = fmaf(w3, v3, acc);
  }
  for (; p < p1; ++p) {
    int s = col[p];
    acc = fmaf(dis[s] * di, h2[(size_t)s * D + lane], acc);
  }
  float r = fmaf(acc, scsh[lane], scsh[64 + lane]);
  if (RELU) r = fmaxf(r, 0.0f);
  out[(size_t)node * D + lane] = r;
}

// ---------------- Global mean pool (batch is sorted) ----------------

__global__ __launch_bounds__(256) void pool_k(const float* __restrict__ h,
                                              const int* __restrict__ batch,
                                              float* __restrict__ psum,
                                              float* __restrict__ pcnt, int n) {
  int lane  = threadIdx.x & 63;
  int wid   = __builtin_amdgcn_readfirstlane((blockIdx.x * blockDim.x + threadIdx.x) >> 6);
  int start = wid * 64;
  if (start >= n) return;
  int end = min(start + 64, n);
  int cur = batch[start];
  float sum = 0.f;
  int run = 0;
  for (int i = start; i < end; ++i) {
    int g = batch[i];                       // wave-uniform
    if (g != cur) {
      atomicAdd(&psum[cur * D + lane], sum);
      if (lane == 0) atomicAdd(&pcnt[cur], (float)run);
      sum = 0.f; run = 0; cur = g;
    }
    sum += h[(size_t)i * D + lane];
    run += 1;
  }
  atomicAdd(&psum[cur * D + lane], sum);
  if (lane == 0) atomicAdd(&pcnt[cur], (float)run);
}

__global__ void pooldiv_k(const float* __restrict__ psum, const float* __restrict__ pcnt,
                          float* __restrict__ hg) {
  int t = blockIdx.x * blockDim.x + threadIdx.x;
  if (t < 64 * D) hg[t] = psum[t] / fmaxf(pcnt[t >> 6], 1.0f);
}

// ---------------- launcher ----------------

extern "C" void kernel_launch(void* const* d_in, const int* in_sizes, int n_in,
                              void* d_out, int out_size, void* d_ws, size_t ws_size,
                              hipStream_t stream) {
  const float* x   = (const float*)d_in[0];
  const int*   ei  = (const int*)d_in[1];
  const int*   bat = (const int*)d_in[2];
  const float* W1  = (const float*)d_in[3];
  const float* W2  = (const float*)d_in[4];
  const float* W3  = (const float*)d_in[5];
  const float* b1  = (const float*)d_in[6];
  const float* b2  = (const float*)d_in[7];
  const float* b3  = (const float*)d_in[8];
  const float* g1  = (const float*)d_in[9];
  const float* be1 = (const float*)d_in[10];
  const float* rm1 = (const float*)d_in[11];
  const float* rv1 = (const float*)d_in[12];
  const float* g2  = (const float*)d_in[13];
  const float* be2 = (const float*)d_in[14];
  const float* rm2 = (const float*)d_in[15];
  const float* rv2 = (const float*)d_in[16];

  const int n = in_sizes[0] / D;   // 100000
  const int e = in_sizes[1] / 2;   // 1200000
  const int* src = ei;
  const int* dst = ei + e;

  char* ws = (char*)d_ws;
  size_t off = 0;
  auto alloc = [&](size_t bytes) -> void* {
    void* p = ws + off;
    off = (off + bytes + 255) & ~(size_t)255;
    return p;
  };
  float* bufA   = (float*)alloc((size_t)n * D * 4);
  float* bufB   = (float*)alloc((size_t)n * D * 4);
  int*   cnt    = (int*)alloc((size_t)n * 4);
  int*   rp     = (int*)alloc((size_t)(n + 1) * 4);
  int*   cursor = (int*)alloc((size_t)n * 4);
  float* dis    = (float*)alloc((size_t)n * 4);
  int*   col    = (int*)alloc((size_t)e * 4);
  int*   bsum   = (int*)alloc(512 * 4);
  int*   boff   = (int*)alloc(512 * 4);
  float* scsh   = (float*)alloc(6 * 64 * 4);
  float* psum   = (float*)alloc(64 * D * 4);
  float* pcnt   = (float*)alloc(64 * 4);

  float* hout = (float*)d_out;                    // [N, D]
  float* hg   = (float*)d_out + (size_t)n * D;    // [G, D]

  hipMemsetAsync(cnt,  0, (size_t)n * 4, stream);
  hipMemsetAsync(psum, 0, 64 * D * 4, stream);
  hipMemsetAsync(pcnt, 0, 64 * 4, stream);

  const int nb = (n + 255) / 256;
  hist_k<<<(e + 255) / 256, 256, 0, stream>>>(dst, cnt, e);
  scan_a_k<<<nb, 256, 0, stream>>>(cnt, rp, bsum, n);
  scan_b_k<<<1, 512, 0, stream>>>(bsum, boff, nb);
  scan_c_k<<<nb, 256, 0, stream>>>(cnt, rp, boff, cursor, dis, n, e);
  fill_k<<<(e + 255) / 256, 256, 0, stream>>>(src, dst, cursor, col, e);
  bnprep_k<<<1, 192, 0, stream>>>(b1, b2, b3, g1, be1, rm1, rv1, g2, be2, rm2, rv2, scsh);

  const int gemm_blocks = (n + GT_R - 1) / GT_R;   // 782
  const int agg_blocks  = (n * 64 + 255) / 256;

  // layer 1
  gemm_k<<<gemm_blocks, 256, 0, stream>>>(x, W1, bufA, n);
  agg_k<true><<<agg_blocks, 256, 0, stream>>>(bufA, rp, col, dis, scsh + 0 * 128, bufB, n);
  // layer 2
  gemm_k<<<gemm_blocks, 256, 0, stream>>>(bufB, W2, bufA, n);
  agg_k<true><<<agg_blocks, 256, 0, stream>>>(bufA, rp, col, dis, scsh + 1 * 128, bufB, n);
  // layer 3 (no BN/ReLU; shift = b3)
  gemm_k<<<gemm_blocks, 256, 0, stream>>>(bufB, W3, bufA, n);
  agg_k<false><<<agg_blocks, 256, 0, stream>>>(bufA, rp, col, dis, scsh + 2 * 128, hout, n);

  // pooling
  const int pool_waves = (n + 63) / 64;
  pool_k<<<(pool_waves * 64 + 255) / 256, 256, 0, stream>>>(hout, bat, psum, pcnt, n);
  pooldiv_k<<<(64 * D + 255) / 256, 256, 0, stream>>>(psum, pcnt, hg);
}

// Round 3
// 386.460 us; speedup vs baseline: 1.4967x; 1.3080x over previous
//
#include <hip/hip_runtime.h>
#include <hip/hip_fp16.h>

#define D 64
#define EPS 1e-5f

// CSR bucketing params: buckets of 512 consecutive dst nodes
#define BK_SHIFT 9
#define BK_W 512
#define NBMAX 256        // supports n up to 131072
#define BK_CAP 8192      // avg 6144 edges/bucket, +26 sigma margin
#define CHUNK 4096       // edges per bucket_k block

// ---------------- Phase A: bucketize edges (one global atomic per bucket per block) ----

__global__ __launch_bounds__(256) void bucket_k(const int* __restrict__ src,
                                                const int* __restrict__ dst,
                                                int* __restrict__ bcnt,
                                                int2* __restrict__ pairs,
                                                int e, int nbk) {
  __shared__ int hcnt[NBMAX];
  __shared__ int hbase[NBMAX];
  const int t = threadIdx.x;
  const int e0 = blockIdx.x * CHUNK;
  const int e1 = min(e0 + CHUNK, e);
  for (int i = t; i < nbk; i += 256) hcnt[i] = 0;
  __syncthreads();
  for (int i = e0 + t; i < e1; i += 256)
    atomicAdd(&hcnt[dst[i] >> BK_SHIFT], 1);
  __syncthreads();
  for (int i = t; i < nbk; i += 256) {
    int c = hcnt[i];
    hbase[i] = c ? atomicAdd(&bcnt[i], c) : 0;
    hcnt[i] = 0;   // reuse as cursor
  }
  __syncthreads();
  for (int i = e0 + t; i < e1; i += 256) {
    int s = src[i], d = dst[i];
    int b = d >> BK_SHIFT;
    int r = hbase[b] + atomicAdd(&hcnt[b], 1);
    if (r < BK_CAP) pairs[(size_t)b * BK_CAP + r] = make_int2(s, d);
  }
}

// ---------------- Phase B1: per-bucket histogram -> cnt (coalesced, no global atomics) --

__global__ __launch_bounds__(256) void bhist_k(const int* __restrict__ bcnt,
                                               const int2* __restrict__ pairs,
                                               int* __restrict__ cnt, int n) {
  __shared__ int h[BK_W];
  const int b = blockIdx.x, t = threadIdx.x;
  const int base = b << BK_SHIFT;
  const int m = min(bcnt[b], BK_CAP);
  for (int i = t; i < BK_W; i += 256) h[i] = 0;
  __syncthreads();
  const int2* p = pairs + (size_t)b * BK_CAP;
  for (int i = t; i < m; i += 256) atomicAdd(&h[p[i].y - base], 1);
  __syncthreads();
  for (int i = t; i < BK_W && base + i < n; i += 256) cnt[base + i] = h[i];
}

// ---------------- scans (unchanged) ----------------

__global__ void scan_a_k(const int* __restrict__ cnt, int* __restrict__ rp,
                         int* __restrict__ bsum, int n) {
  __shared__ int sm[256];
  int t = threadIdx.x, i = blockIdx.x * 256 + t;
  int v = (i < n) ? cnt[i] : 0;
  sm[t] = v; __syncthreads();
  for (int off = 1; off < 256; off <<= 1) {
    int x = (t >= off) ? sm[t - off] : 0; __syncthreads();
    sm[t] += x; __syncthreads();
  }
  if (i < n) rp[i] = sm[t] - v;
  if (t == 255) bsum[blockIdx.x] = sm[t];
}

__global__ void scan_b_k(const int* __restrict__ bsum, int* __restrict__ boff, int nb) {
  __shared__ int sm[512];
  int t = threadIdx.x;
  int v = (t < nb) ? bsum[t] : 0;
  sm[t] = v; __syncthreads();
  for (int off = 1; off < 512; off <<= 1) {
    int x = (t >= off) ? sm[t - off] : 0; __syncthreads();
    sm[t] += x; __syncthreads();
  }
  boff[t] = sm[t] - v;
}

__global__ void scan_c_k(const int* __restrict__ cnt, int* __restrict__ rp,
                         const int* __restrict__ boff,
                         float* __restrict__ dis, int n, int etot) {
  int i = blockIdx.x * blockDim.x + threadIdx.x;
  if (i < n) {
    rp[i] = rp[i] + boff[i >> 8];
    dis[i] = rsqrtf((float)cnt[i] + 1.0f);
  }
  if (i == 0) rp[n] = etot;
}

// ---------------- Phase B2: place into CSR (LDS cursors + coalesced copy-out) ---------

__global__ __launch_bounds__(256) void place_k(const int* __restrict__ bcnt,
                                               const int2* __restrict__ pairs,
                                               const int* __restrict__ rp,
                                               int* __restrict__ col, int n) {
  __shared__ int cur[BK_W];
  __shared__ int stage[BK_CAP];
  const int b = blockIdx.x, t = threadIdx.x;
  const int base = b << BK_SHIFT;
  const int out0 = rp[base];
  const int m = min(bcnt[b], BK_CAP);
  for (int i = t; i < BK_W; i += 256) {
    int node = base + i;
    cur[i] = (node < n) ? rp[node] - out0 : 0;
  }
  __syncthreads();
  const int2* p = pairs + (size_t)b * BK_CAP;
  for (int i = t; i < m; i += 256) {
    int2 sd = p[i];
    int r = atomicAdd(&cur[sd.y - base], 1);
    stage[r] = sd.x;
  }
  __syncthreads();
  for (int i = t; i < m; i += 256) col[out0 + i] = stage[i];
}

// ---------------- BN/bias folding ----------------

__global__ void bnprep_k(const float* __restrict__ b1, const float* __restrict__ b2,
                         const float* __restrict__ b3,
                         const float* __restrict__ g1, const float* __restrict__ be1,
                         const float* __restrict__ rm1, const float* __restrict__ rv1,
                         const float* __restrict__ g2, const float* __restrict__ be2,
                         const float* __restrict__ rm2, const float* __restrict__ rv2,
                         float* __restrict__ scsh) {
  int t = threadIdx.x;
  int j = t & 63, l = t >> 6;
  float sc, sh;
  if (l == 0)      { sc = g1[j] * rsqrtf(rv1[j] + EPS); sh = (b1[j] - rm1[j]) * sc + be1[j]; }
  else if (l == 1) { sc = g2[j] * rsqrtf(rv2[j] + EPS); sh = (b2[j] - rm2[j]) * sc + be2[j]; }
  else             { sc = 1.0f;                          sh = b3[j]; }
  scsh[l * 128 + j] = sc;
  scsh[l * 128 + 64 + j] = sh;
}

// ---------------- GEMM: fp32 in, fp16 out; LDS-tiled 128x64, 8x4 micro-tile ----------

#define GT_R 128
#define XT_LD 132

__global__ __launch_bounds__(256) void gemm_k(const float* __restrict__ in,
                                              const float* __restrict__ W,
                                              __half* __restrict__ out, int nrows) {
  __shared__ float ws[64 * 64];
  __shared__ float xt[64 * XT_LD];

  const int t    = threadIdx.x;
  const int lane = t & 63;
  const int w    = t >> 6;
  const int row0 = blockIdx.x * GT_R;

  for (int i = t; i < 1024; i += 256)
    ((float4*)ws)[i] = ((const float4*)W)[i];

#pragma unroll
  for (int j = 0; j < 8; ++j) {
    int Q = w + 4 * j;
    int r = row0 + 4 * Q;
    float4 v;
    v.x = (r + 0 < nrows) ? in[(size_t)(r + 0) * D + lane] : 0.f;
    v.y = (r + 1 < nrows) ? in[(size_t)(r + 1) * D + lane] : 0.f;
    v.z = (r + 2 < nrows) ? in[(size_t)(r + 2) * D + lane] : 0.f;
    v.w = (r + 3 < nrows) ? in[(size_t)(r + 3) * D + lane] : 0.f;
    *(float4*)&xt[lane * XT_LD + 4 * Q] = v;
  }
  __syncthreads();

  const int cq = (t & 15) * 4;
  const int rg = (t >> 4) * 8;
  float acc[8][4] = {};

#pragma unroll 4
  for (int k = 0; k < 64; ++k) {
    float4 b   = *(const float4*)&ws[k * 64 + cq];
    float4 alo = *(const float4*)&xt[k * XT_LD + rg];
    float4 ahi = *(const float4*)&xt[k * XT_LD + rg + 4];
    const float ar[8] = {alo.x, alo.y, alo.z, alo.w, ahi.x, ahi.y, ahi.z, ahi.w};
#pragma unroll
    for (int i = 0; i < 8; ++i) {
      acc[i][0] = fmaf(ar[i], b.x, acc[i][0]);
      acc[i][1] = fmaf(ar[i], b.y, acc[i][1]);
      acc[i][2] = fmaf(ar[i], b.z, acc[i][2]);
      acc[i][3] = fmaf(ar[i], b.w, acc[i][3]);
    }
  }

#pragma unroll
  for (int i = 0; i < 8; ++i) {
    int r = row0 + rg + i;
    if (r < nrows) {
      union { __half2 h[2]; float2 f; } u;
      u.h[0] = __floats2half2_rn(acc[i][0], acc[i][1]);
      u.h[1] = __floats2half2_rn(acc[i][2], acc[i][3]);
      *(float2*)&out[(size_t)r * D + cq] = u.f;
    }
  }
}

// ---------------- Aggregation: one wave per dst node, lane = feature, fp16 gather -----

template <bool RELU>
__global__ __launch_bounds__(256) void agg_k(const __half* __restrict__ h2,
                                             const int* __restrict__ rp,
                                             const int* __restrict__ col,
                                             const float* __restrict__ dis,
                                             const float* __restrict__ scsh,
                                             float* __restrict__ out, int n) {
  int lane = threadIdx.x & 63;
  int node = __builtin_amdgcn_readfirstlane((blockIdx.x * blockDim.x + threadIdx.x) >> 6);
  if (node >= n) return;
  float di  = dis[node];
  float acc = di * di * __half2float(h2[(size_t)node * D + lane]);
  int p  = rp[node];
  int p1 = rp[node + 1];
  for (; p + 3 < p1; p += 4) {
    int s0 = col[p], s1 = col[p + 1], s2 = col[p + 2], s3 = col[p + 3];
    float w0 = dis[s0] * di, w1 = dis[s1] * di;
    float w2 = dis[s2] * di, w3 = dis[s3] * di;
    float v0 = __half2float(h2[(size_t)s0 * D + lane]);
    float v1 = __half2float(h2[(size_t)s1 * D + lane]);
    float v2 = __half2float(h2[(size_t)s2 * D + lane]);
    float v3 = __half2float(h2[(size_t)s3 * D + lane]);
    acc = fmaf(w0, v0, acc);
    acc = fmaf(w1, v1, acc);
    acc = fmaf(w2, v2, acc);
    acc = fmaf(w3, v3, acc);
  }
  for (; p < p1; ++p) {
    int s = col[p];
    acc = fmaf(dis[s] * di, __half2float(h2[(size_t)s * D + lane]), acc);
  }
  float r = fmaf(acc, scsh[lane], scsh[64 + lane]);
  if (RELU) r = fmaxf(r, 0.0f);
  out[(size_t)node * D + lane] = r;
}

// ---------------- Global mean pool (batch is sorted) ----------------

__global__ __launch_bounds__(256) void pool_k(const float* __restrict__ h,
                                              const int* __restrict__ batch,
                                              float* __restrict__ psum,
                                              float* __restrict__ pcnt, int n) {
  int lane  = threadIdx.x & 63;
  int wid   = __builtin_amdgcn_readfirstlane((blockIdx.x * blockDim.x + threadIdx.x) >> 6);
  int start = wid * 64;
  if (start >= n) return;
  int end = min(start + 64, n);
  int cur = batch[start];
  float sum = 0.f;
  int run = 0;
  for (int i = start; i < end; ++i) {
    int g = batch[i];
    if (g != cur) {
      atomicAdd(&psum[cur * D + lane], sum);
      if (lane == 0) atomicAdd(&pcnt[cur], (float)run);
      sum = 0.f; run = 0; cur = g;
    }
    sum += h[(size_t)i * D + lane];
    run += 1;
  }
  atomicAdd(&psum[cur * D + lane], sum);
  if (lane == 0) atomicAdd(&pcnt[cur], (float)run);
}

__global__ void pooldiv_k(const float* __restrict__ psum, const float* __restrict__ pcnt,
                          float* __restrict__ hg) {
  int t = blockIdx.x * blockDim.x + threadIdx.x;
  if (t < 64 * D) hg[t] = psum[t] / fmaxf(pcnt[t >> 6], 1.0f);
}

// ---------------- launcher ----------------

extern "C" void kernel_launch(void* const* d_in, const int* in_sizes, int n_in,
                              void* d_out, int out_size, void* d_ws, size_t ws_size,
                              hipStream_t stream) {
  const float* x   = (const float*)d_in[0];
  const int*   ei  = (const int*)d_in[1];
  const int*   bat = (const int*)d_in[2];
  const float* W1  = (const float*)d_in[3];
  const float* W2  = (const float*)d_in[4];
  const float* W3  = (const float*)d_in[5];
  const float* b1  = (const float*)d_in[6];
  const float* b2  = (const float*)d_in[7];
  const float* b3  = (const float*)d_in[8];
  const float* g1  = (const float*)d_in[9];
  const float* be1 = (const float*)d_in[10];
  const float* rm1 = (const float*)d_in[11];
  const float* rv1 = (const float*)d_in[12];
  const float* g2  = (const float*)d_in[13];
  const float* be2 = (const float*)d_in[14];
  const float* rm2 = (const float*)d_in[15];
  const float* rv2 = (const float*)d_in[16];

  const int n = in_sizes[0] / D;   // 100000
  const int e = in_sizes[1] / 2;   // 1200000
  const int* src = ei;
  const int* dst = ei + e;
  const int nbk = (n + BK_W - 1) >> BK_SHIFT;   // 196

  char* ws = (char*)d_ws;
  size_t off = 0;
  auto alloc = [&](size_t bytes) -> void* {
    void* p = ws + off;
    off = (off + bytes + 255) & ~(size_t)255;
    return p;
  };
  float*  bufB = (float*)alloc((size_t)n * D * 4);     // agg fp32 out (layers 1,2)
  int2*   pairs = (int2*)bufB;                         // aliases bufB; dead before agg1
  __half* hbuf = (__half*)alloc((size_t)n * D * 2);    // gemm fp16 out
  int*    cnt  = (int*)alloc((size_t)n * 4);
  int*    rp   = (int*)alloc((size_t)(n + 1) * 4);
  float*  dis  = (float*)alloc((size_t)n * 4);
  int*    col  = (int*)alloc((size_t)e * 4);
  int*    bcnt = (int*)alloc(NBMAX * 4);
  int*    bsum = (int*)alloc(512 * 4);
  int*    boff = (int*)alloc(512 * 4);
  float*  scsh = (float*)alloc(6 * 64 * 4);
  float*  psum = (float*)alloc(64 * D * 4);
  float*  pcnt = (float*)alloc(64 * 4);

  float* hout = (float*)d_out;
  float* hg   = (float*)d_out + (size_t)n * D;

  hipMemsetAsync(bcnt, 0, NBMAX * 4, stream);
  hipMemsetAsync(psum, 0, 64 * D * 4, stream);
  hipMemsetAsync(pcnt, 0, 64 * 4, stream);

  const int nb = (n + 255) / 256;
  bucket_k<<<(e + CHUNK - 1) / CHUNK, 256, 0, stream>>>(src, dst, bcnt, pairs, e, nbk);
  bhist_k<<<nbk, 256, 0, stream>>>(bcnt, pairs, cnt, n);
  scan_a_k<<<nb, 256, 0, stream>>>(cnt, rp, bsum, n);
  scan_b_k<<<1, 512, 0, stream>>>(bsum, boff, nb);
  scan_c_k<<<nb, 256, 0, stream>>>(cnt, rp, boff, dis, n, e);
  place_k<<<nbk, 256, 0, stream>>>(bcnt, pairs, rp, col, n);
  bnprep_k<<<1, 192, 0, stream>>>(b1, b2, b3, g1, be1, rm1, rv1, g2, be2, rm2, rv2, scsh);

  const int gemm_blocks = (n + GT_R - 1) / GT_R;
  const int agg_blocks  = (n * 64 + 255) / 256;

  // layer 1
  gemm_k<<<gemm_blocks, 256, 0, stream>>>(x, W1, hbuf, n);
  agg_k<true><<<agg_blocks, 256, 0, stream>>>(hbuf, rp, col, dis, scsh + 0 * 128, bufB, n);
  // layer 2
  gemm_k<<<gemm_blocks, 256, 0, stream>>>(bufB, W2, hbuf, n);
  agg_k<true><<<agg_blocks, 256, 0, stream>>>(hbuf, rp, col, dis, scsh + 1 * 128, bufB, n);
  // layer 3
  gemm_k<<<gemm_blocks, 256, 0, stream>>>(bufB, W3, hbuf, n);
  agg_k<false><<<agg_blocks, 256, 0, stream>>>(hbuf, rp, col, dis, scsh + 2 * 128, hout, n);

  // pooling
  const int pool_waves = (n + 63) / 64;
  pool_k<<<(pool_waves * 64 + 255) / 256, 256, 0, stream>>>(hout, bat, psum, pcnt, n);
  pooldiv_k<<<(64 * D + 255) / 256, 256, 0, stream>>>(psum, pcnt, hg);
}

// Round 4
// 376.447 us; speedup vs baseline: 1.5366x; 1.0266x over previous
//
#include <hip/hip_runtime.h>
#include <hip/hip_fp16.h>

#define D 64
#define EPS 1e-5f

// CSR bucketing params: buckets of 512 consecutive dst nodes
#define BK_SHIFT 9
#define BK_W 512
#define NBMAX 256        // supports n up to 131072
#define BK_CAP 8192      // avg 6144 edges/bucket
#define CHUNK 4096       // edges per bucket_k block

// ---------------- Phase A: bucketize edges; pack (src<<9 | dst_local) ----------------

__global__ __launch_bounds__(256) void bucket_k(const int* __restrict__ src,
                                                const int* __restrict__ dst,
                                                int* __restrict__ bcnt,
                                                int* __restrict__ pairs,
                                                int e, int nbk) {
  __shared__ int hcnt[NBMAX];
  __shared__ int hbase[NBMAX];
  const int t = threadIdx.x;
  const int e0 = blockIdx.x * CHUNK;
  const int e1 = min(e0 + CHUNK, e);
  for (int i = t; i < nbk; i += 256) hcnt[i] = 0;
  __syncthreads();
  for (int i = e0 + t; i < e1; i += 256)
    atomicAdd(&hcnt[dst[i] >> BK_SHIFT], 1);
  __syncthreads();
  for (int i = t; i < nbk; i += 256) {
    int c = hcnt[i];
    hbase[i] = c ? atomicAdd(&bcnt[i], c) : 0;
    hcnt[i] = 0;   // reuse as cursor
  }
  __syncthreads();
  for (int i = e0 + t; i < e1; i += 256) {
    int s = src[i], d = dst[i];
    int b = d >> BK_SHIFT;
    int r = hbase[b] + atomicAdd(&hcnt[b], 1);
    if (r < BK_CAP) pairs[(size_t)b * BK_CAP + r] = (s << BK_SHIFT) | (d & (BK_W - 1));
  }
}

// ---------------- Phase B1: per-bucket histogram -> cnt ----------------

__global__ __launch_bounds__(256) void bhist_k(const int* __restrict__ bcnt,
                                               const int* __restrict__ pairs,
                                               int* __restrict__ cnt, int n) {
  __shared__ int h[BK_W];
  const int b = blockIdx.x, t = threadIdx.x;
  const int base = b << BK_SHIFT;
  const int m = min(bcnt[b], BK_CAP);
  for (int i = t; i < BK_W; i += 256) h[i] = 0;
  __syncthreads();
  const int* p = pairs + (size_t)b * BK_CAP;
  for (int i = t; i < m; i += 256) atomicAdd(&h[p[i] & (BK_W - 1)], 1);
  __syncthreads();
  for (int i = t; i < BK_W && base + i < n; i += 256) cnt[base + i] = h[i];
}

// ---------------- scans ----------------

__global__ void scan_a_k(const int* __restrict__ cnt, int* __restrict__ rp,
                         int* __restrict__ bsum, int n) {
  __shared__ int sm[256];
  int t = threadIdx.x, i = blockIdx.x * 256 + t;
  int v = (i < n) ? cnt[i] : 0;
  sm[t] = v; __syncthreads();
  for (int off = 1; off < 256; off <<= 1) {
    int x = (t >= off) ? sm[t - off] : 0; __syncthreads();
    sm[t] += x; __syncthreads();
  }
  if (i < n) rp[i] = sm[t] - v;
  if (t == 255) bsum[blockIdx.x] = sm[t];
}

__global__ void scan_b_k(const int* __restrict__ bsum, int* __restrict__ boff, int nb) {
  __shared__ int sm[512];
  int t = threadIdx.x;
  int v = (t < nb) ? bsum[t] : 0;
  sm[t] = v; __syncthreads();
  for (int off = 1; off < 512; off <<= 1) {
    int x = (t >= off) ? sm[t - off] : 0; __syncthreads();
    sm[t] += x; __syncthreads();
  }
  boff[t] = sm[t] - v;
}

__global__ void scan_c_k(const int* __restrict__ cnt, int* __restrict__ rp,
                         const int* __restrict__ boff,
                         float* __restrict__ dis, int n, int etot) {
  int i = blockIdx.x * blockDim.x + threadIdx.x;
  if (i < n) {
    rp[i] = rp[i] + boff[i >> 8];
    dis[i] = rsqrtf((float)cnt[i] + 1.0f);
  }
  if (i == 0) rp[n] = etot;
}

// ---------------- Phase B2: place into CSR ----------------

__global__ __launch_bounds__(256) void place_k(const int* __restrict__ bcnt,
                                               const int* __restrict__ pairs,
                                               const int* __restrict__ rp,
                                               int* __restrict__ col, int n) {
  __shared__ int cur[BK_W];
  __shared__ int stage[BK_CAP];
  const int b = blockIdx.x, t = threadIdx.x;
  const int base = b << BK_SHIFT;
  const int out0 = rp[base];
  const int m = min(bcnt[b], BK_CAP);
  for (int i = t; i < BK_W; i += 256) {
    int node = base + i;
    cur[i] = (node < n) ? rp[node] - out0 : 0;
  }
  __syncthreads();
  const int* p = pairs + (size_t)b * BK_CAP;
  for (int i = t; i < m; i += 256) {
    int pk = p[i];
    int r = atomicAdd(&cur[pk & (BK_W - 1)], 1);
    stage[r] = pk >> BK_SHIFT;
  }
  __syncthreads();
  for (int i = t; i < m; i += 256) col[out0 + i] = stage[i];
}

// ---------------- BN/bias folding ----------------

__global__ void bnprep_k(const float* __restrict__ b1, const float* __restrict__ b2,
                         const float* __restrict__ b3,
                         const float* __restrict__ g1, const float* __restrict__ be1,
                         const float* __restrict__ rm1, const float* __restrict__ rv1,
                         const float* __restrict__ g2, const float* __restrict__ be2,
                         const float* __restrict__ rm2, const float* __restrict__ rv2,
                         float* __restrict__ scsh) {
  int t = threadIdx.x;
  int j = t & 63, l = t >> 6;
  float sc, sh;
  if (l == 0)      { sc = g1[j] * rsqrtf(rv1[j] + EPS); sh = (b1[j] - rm1[j]) * sc + be1[j]; }
  else if (l == 1) { sc = g2[j] * rsqrtf(rv2[j] + EPS); sh = (b2[j] - rm2[j]) * sc + be2[j]; }
  else             { sc = 1.0f;                          sh = b3[j]; }
  scsh[l * 128 + j] = sc;
  scsh[l * 128 + 64 + j] = sh;
}

// ---------------- GEMM: out[r] = dis[r] * (in[r] @ W), fp16 out ----------------

#define GT_R 128
#define XT_LD 132

__global__ __launch_bounds__(256) void gemm_k(const float* __restrict__ in,
                                              const float* __restrict__ W,
                                              const float* __restrict__ dis,
                                              __half* __restrict__ out, int nrows) {
  __shared__ float ws[64 * 64];
  __shared__ float xt[64 * XT_LD];
  __shared__ float dtile[GT_R];

  const int t    = threadIdx.x;
  const int lane = t & 63;
  const int w    = t >> 6;
  const int row0 = blockIdx.x * GT_R;

  for (int i = t; i < 1024; i += 256)
    ((float4*)ws)[i] = ((const float4*)W)[i];

  if (t < GT_R) {
    int r = row0 + t;
    dtile[t] = (r < nrows) ? dis[r] : 0.f;
  }

#pragma unroll
  for (int j = 0; j < 8; ++j) {
    int Q = w + 4 * j;
    int r = row0 + 4 * Q;
    float4 v;
    v.x = (r + 0 < nrows) ? in[(size_t)(r + 0) * D + lane] : 0.f;
    v.y = (r + 1 < nrows) ? in[(size_t)(r + 1) * D + lane] : 0.f;
    v.z = (r + 2 < nrows) ? in[(size_t)(r + 2) * D + lane] : 0.f;
    v.w = (r + 3 < nrows) ? in[(size_t)(r + 3) * D + lane] : 0.f;
    *(float4*)&xt[lane * XT_LD + 4 * Q] = v;
  }
  __syncthreads();

  const int cq = (t & 15) * 4;
  const int rg = (t >> 4) * 8;
  float acc[8][4] = {};

#pragma unroll 4
  for (int k = 0; k < 64; ++k) {
    float4 b   = *(const float4*)&ws[k * 64 + cq];
    float4 alo = *(const float4*)&xt[k * XT_LD + rg];
    float4 ahi = *(const float4*)&xt[k * XT_LD + rg + 4];
    const float ar[8] = {alo.x, alo.y, alo.z, alo.w, ahi.x, ahi.y, ahi.z, ahi.w};
#pragma unroll
    for (int i = 0; i < 8; ++i) {
      acc[i][0] = fmaf(ar[i], b.x, acc[i][0]);
      acc[i][1] = fmaf(ar[i], b.y, acc[i][1]);
      acc[i][2] = fmaf(ar[i], b.z, acc[i][2]);
      acc[i][3] = fmaf(ar[i], b.w, acc[i][3]);
    }
  }

#pragma unroll
  for (int i = 0; i < 8; ++i) {
    int r = row0 + rg + i;
    if (r < nrows) {
      float dsc = dtile[rg + i];
      union { __half2 h[2]; float2 f; } u;
      u.h[0] = __floats2half2_rn(dsc * acc[i][0], dsc * acc[i][1]);
      u.h[1] = __floats2half2_rn(dsc * acc[i][2], dsc * acc[i][3]);
      *(float2*)&out[(size_t)r * D + cq] = u.f;
    }
  }
}

// ---------------- Aggregation: cooperative col fetch + readlane broadcast ----------
// h2s is pre-scaled by dis[src]; out = RELU?((di * (self + sum)) * sc + sh)

template <bool RELU>
__global__ __launch_bounds__(256) void agg_k(const __half* __restrict__ h2s,
                                             const int* __restrict__ rp,
                                             const int* __restrict__ col,
                                             const float* __restrict__ dis,
                                             const float* __restrict__ scsh,
                                             float* __restrict__ out, int n) {
  int lane = threadIdx.x & 63;
  int node = __builtin_amdgcn_readfirstlane((blockIdx.x * blockDim.x + threadIdx.x) >> 6);
  if (node >= n) return;
  float acc = __half2float(h2s[(size_t)node * D + lane]);   // self-loop term
  int p  = rp[node];
  int p1 = rp[node + 1];
  while (p < p1) {
    int m = min(p1 - p, 64);
    int idxv = 0;
    if (lane < m) idxv = col[p + lane];    // one vector load = up to 64 indices
    int e = 0;
    for (; e + 3 < m; e += 4) {
      int s0 = __builtin_amdgcn_readlane(idxv, e);
      int s1 = __builtin_amdgcn_readlane(idxv, e + 1);
      int s2 = __builtin_amdgcn_readlane(idxv, e + 2);
      int s3 = __builtin_amdgcn_readlane(idxv, e + 3);
      float v0 = __half2float(h2s[(size_t)s0 * D + lane]);
      float v1 = __half2float(h2s[(size_t)s1 * D + lane]);
      float v2 = __half2float(h2s[(size_t)s2 * D + lane]);
      float v3 = __half2float(h2s[(size_t)s3 * D + lane]);
      acc += v0; acc += v1; acc += v2; acc += v3;
    }
    for (; e < m; ++e) {
      int s = __builtin_amdgcn_readlane(idxv, e);
      acc += __half2float(h2s[(size_t)s * D + lane]);
    }
    p += m;
  }
  float di = dis[node];
  float r = fmaf(di * acc, scsh[lane], scsh[64 + lane]);
  if (RELU) r = fmaxf(r, 0.0f);
  out[(size_t)node * D + lane] = r;
}

// ---------------- Global mean pool (batch is sorted) ----------------

__global__ __launch_bounds__(256) void pool_k(const float* __restrict__ h,
                                              const int* __restrict__ batch,
                                              float* __restrict__ psum,
                                              float* __restrict__ pcnt, int n) {
  int lane  = threadIdx.x & 63;
  int wid   = __builtin_amdgcn_readfirstlane((blockIdx.x * blockDim.x + threadIdx.x) >> 6);
  int start = wid * 64;
  if (start >= n) return;
  int end = min(start + 64, n);
  int cur = batch[start];
  float sum = 0.f;
  int run = 0;
  for (int i = start; i < end; ++i) {
    int g = batch[i];
    if (g != cur) {
      atomicAdd(&psum[cur * D + lane], sum);
      if (lane == 0) atomicAdd(&pcnt[cur], (float)run);
      sum = 0.f; run = 0; cur = g;
    }
    sum += h[(size_t)i * D + lane];
    run += 1;
  }
  atomicAdd(&psum[cur * D + lane], sum);
  if (lane == 0) atomicAdd(&pcnt[cur], (float)run);
}

__global__ void pooldiv_k(const float* __restrict__ psum, const float* __restrict__ pcnt,
                          float* __restrict__ hg) {
  int t = blockIdx.x * blockDim.x + threadIdx.x;
  if (t < 64 * D) hg[t] = psum[t] / fmaxf(pcnt[t >> 6], 1.0f);
}

// ---------------- launcher ----------------

extern "C" void kernel_launch(void* const* d_in, const int* in_sizes, int n_in,
                              void* d_out, int out_size, void* d_ws, size_t ws_size,
                              hipStream_t stream) {
  const float* x   = (const float*)d_in[0];
  const int*   ei  = (const int*)d_in[1];
  const int*   bat = (const int*)d_in[2];
  const float* W1  = (const float*)d_in[3];
  const float* W2  = (const float*)d_in[4];
  const float* W3  = (const float*)d_in[5];
  const float* b1  = (const float*)d_in[6];
  const float* b2  = (const float*)d_in[7];
  const float* b3  = (const float*)d_in[8];
  const float* g1  = (const float*)d_in[9];
  const float* be1 = (const float*)d_in[10];
  const float* rm1 = (const float*)d_in[11];
  const float* rv1 = (const float*)d_in[12];
  const float* g2  = (const float*)d_in[13];
  const float* be2 = (const float*)d_in[14];
  const float* rm2 = (const float*)d_in[15];
  const float* rv2 = (const float*)d_in[16];

  const int n = in_sizes[0] / D;   // 100000
  const int e = in_sizes[1] / 2;   // 1200000
  const int* src = ei;
  const int* dst = ei + e;
  const int nbk = (n + BK_W - 1) >> BK_SHIFT;   // 196

  char* ws = (char*)d_ws;
  size_t off = 0;
  auto alloc = [&](size_t bytes) -> void* {
    void* p = ws + off;
    off = (off + bytes + 255) & ~(size_t)255;
    return p;
  };
  float*  bufB = (float*)alloc((size_t)n * D * 4);     // agg fp32 out (layers 1,2)
  int*    pairs = (int*)bufB;                          // aliases bufB; dead before agg1
  __half* hbuf = (__half*)alloc((size_t)n * D * 2);    // gemm fp16 out (dis-scaled)
  int*    cnt  = (int*)alloc((size_t)n * 4);
  int*    rp   = (int*)alloc((size_t)(n + 1) * 4);
  float*  dis  = (float*)alloc((size_t)n * 4);
  int*    col  = (int*)alloc((size_t)e * 4);
  int*    bcnt = (int*)alloc(NBMAX * 4);
  int*    bsum = (int*)alloc(512 * 4);
  int*    boff = (int*)alloc(512 * 4);
  float*  scsh = (float*)alloc(6 * 64 * 4);
  float*  psum = (float*)alloc(64 * D * 4);
  float*  pcnt = (float*)alloc(64 * 4);

  float* hout = (float*)d_out;
  float* hg   = (float*)d_out + (size_t)n * D;

  hipMemsetAsync(bcnt, 0, NBMAX * 4, stream);
  hipMemsetAsync(psum, 0, 64 * D * 4, stream);
  hipMemsetAsync(pcnt, 0, 64 * 4, stream);

  const int nb = (n + 255) / 256;
  bucket_k<<<(e + CHUNK - 1) / CHUNK, 256, 0, stream>>>(src, dst, bcnt, pairs, e, nbk);
  bhist_k<<<nbk, 256, 0, stream>>>(bcnt, pairs, cnt, n);
  scan_a_k<<<nb, 256, 0, stream>>>(cnt, rp, bsum, n);
  scan_b_k<<<1, 512, 0, stream>>>(bsum, boff, nb);
  scan_c_k<<<nb, 256, 0, stream>>>(cnt, rp, boff, dis, n, e);
  place_k<<<nbk, 256, 0, stream>>>(bcnt, pairs, rp, col, n);
  bnprep_k<<<1, 192, 0, stream>>>(b1, b2, b3, g1, be1, rm1, rv1, g2, be2, rm2, rv2, scsh);

  const int gemm_blocks = (n + GT_R - 1) / GT_R;
  const int agg_blocks  = (n * 64 + 255) / 256;

  // layer 1
  gemm_k<<<gemm_blocks, 256, 0, stream>>>(x, W1, dis, hbuf, n);
  agg_k<true><<<agg_blocks, 256, 0, stream>>>(hbuf, rp, col, dis, scsh + 0 * 128, bufB, n);
  // layer 2
  gemm_k<<<gemm_blocks, 256, 0, stream>>>(bufB, W2, dis, hbuf, n);
  agg_k<true><<<agg_blocks, 256, 0, stream>>>(hbuf, rp, col, dis, scsh + 1 * 128, bufB, n);
  // layer 3
  gemm_k<<<gemm_blocks, 256, 0, stream>>>(bufB, W3, dis, hbuf, n);
  agg_k<false><<<agg_blocks, 256, 0, stream>>>(hbuf, rp, col, dis, scsh + 2 * 128, hout, n);

  // pooling
  const int pool_waves = (n + 63) / 64;
  pool_k<<<(pool_waves * 64 + 255) / 256, 256, 0, stream>>>(hout, bat, psum, pcnt, n);
  pooldiv_k<<<(64 * D + 255) / 256, 256, 0, stream>>>(psum, pcnt, hg);
}